// Round 7
// baseline (209.189 us; speedup 1.0000x reference)
//
#include <hip/hip_runtime.h>
#include <math.h>

// Problem constants (16 x 1 x 1024 x 1024 fp32 pred/mask -> scalar fp32 loss)
#define BATCH 16
#define H 1024
#define W 1024

// d_ws layout: part[(c*BATCH + b)*NTILES + tile], c in [0,5).
// NO atomics (R4: 5 atomicAdds/block to one 320B region serialized the whole GPU
// at ~115 atomics/us). Per-block partials to unique addresses; finalize reduces.
//
// Tile-shape rationale (R6 post-mortem): at TILE=64/512thr, scan phases used only
// 384/512 threads (waves 6-7 idle through phases 0-2) and LDS 37.9KB capped
// residency at ~2.5 blocks/CU -> ~45% convoy slack (VALU 55%, LDS ~45%, HBM 20%).
// TILE=32/256thr: scans use ALL threads (64 rows x 4 = 64 cols x 4 = 256), LDS
// 16.6KB -> 8 blocks/CU = 32 waves (hw max) of independent convoys. R4's 700us
// at this shape was the atomic wall (6.5% VALU), not the shape.
// TILE=32 partials need 320KB of d_ws -> gated on ws_size, TILE=64 fallback.

// DPP wave64 sum: after these 6 steps lane 63 holds the sum of all 64 lanes.
// old=0 makes invalid-source lanes contribute 0 regardless of bound_ctrl polarity.
__device__ __forceinline__ float wave_sum_dpp(float x) {
    int t;
    t = __builtin_amdgcn_update_dpp(0, __float_as_int(x), 0x111, 0xf, 0xf, true); // row_shr:1
    x += __int_as_float(t);
    t = __builtin_amdgcn_update_dpp(0, __float_as_int(x), 0x112, 0xf, 0xf, true); // row_shr:2
    x += __int_as_float(t);
    t = __builtin_amdgcn_update_dpp(0, __float_as_int(x), 0x114, 0xf, 0xf, true); // row_shr:4
    x += __int_as_float(t);
    t = __builtin_amdgcn_update_dpp(0, __float_as_int(x), 0x118, 0xf, 0xf, true); // row_shr:8
    x += __int_as_float(t);
    t = __builtin_amdgcn_update_dpp(0, __float_as_int(x), 0x142, 0xf, 0xf, true); // row_bcast:15
    x += __int_as_float(t);
    t = __builtin_amdgcn_update_dpp(0, __float_as_int(x), 0x143, 0xf, 0xf, true); // row_bcast:31
    x += __int_as_float(t);
    return x;  // valid in lane 63
}

template<int TILE_, int THREADS_>
__global__ __launch_bounds__(THREADS_)
void adaptive_loss_main(const float* __restrict__ pred,
                        const float* __restrict__ mask,
                        float* __restrict__ part) {
    constexpr int HDIM_  = TILE_ + 32;        // halo grid (16 each side)
    constexpr int SCOLS_ = HDIM_ + 1;         // 97 or 65; %32==1 -> 2-way banks (free)
    constexpr int SEG_   = HDIM_ / 4;         // scan segment per thread (24 or 16)
    constexpr int WAVES_ = THREADS_ / 64;     // 8 or 4
    constexpr int XT_    = TILE_ / 4;         // threads per pixel row (16 or 8)
    constexpr int RPG_   = THREADS_ / XT_;    // pixel rows per group (32)
    constexpr int GROUPS_= TILE_ / RPG_;      // 2 or 1
    constexpr int TX_    = W / TILE_;

    __shared__ float sat[HDIM_ * SCOLS_];
    __shared__ float red[WAVES_][5];

    const int tid = threadIdx.x;
    const int b   = blockIdx.z;
    const int ty0 = blockIdx.y * TILE_;
    const int tx0 = blockIdx.x * TILE_;
    const float* mimg = mask + (size_t)b * H * W;
    const float* pimg = pred + (size_t)b * H * W;

    // ---- Fused phase 0+1: load row segment straight from global (SEG_/4 x float4),
    //      prefix in registers, shfl-combine the 4 segment totals (adjacent lanes),
    //      write the row-scanned values to LDS once. ----
    if (tid < 4 * HDIM_) {
        const int row = tid >> 2, seg = tid & 3;
        const int gy  = ty0 - 16 + row;
        const int gx0 = tx0 - 16 + seg * SEG_;
        const bool rowok = (gy >= 0) && (gy < H);
        const float* rp = mimg + (size_t)gy * W;

        float v[SEG_];
        #pragma unroll
        for (int j = 0; j < SEG_ / 4; ++j) {
            int gx = gx0 + 4 * j;                  // 16B-aligned; chunk fully in or fully out
            float4 t;
            if (rowok && gx >= 0 && gx < W) t = *(const float4*)(rp + gx);
            else                            t = make_float4(0.f, 0.f, 0.f, 0.f);
            v[4 * j + 0] = t.x; v[4 * j + 1] = t.y;
            v[4 * j + 2] = t.z; v[4 * j + 3] = t.w;
        }
        #pragma unroll
        for (int i = 1; i < SEG_; ++i) v[i] += v[i - 1];
        float tot = v[SEG_ - 1];
        float inc = tot;
        float t1 = __shfl_up(inc, 1); if (seg >= 1) inc += t1;
        float t2 = __shfl_up(inc, 2); if (seg >= 2) inc += t2;
        const float off = inc - tot;               // exclusive prefix of segment totals
        const int base = row * SCOLS_ + seg * SEG_;
        #pragma unroll
        for (int i = 0; i < SEG_; ++i) sat[base + i] = v[i] + off;
    }
    __syncthreads();

    // ---- Prefetch phase-3 operands into the col-scan latency window. ----
    float4 m4[GROUPS_], p4[GROUPS_];
    #pragma unroll
    for (int i = 0; i < GROUPS_; ++i) {
        int y  = (tid / XT_) + RPG_ * i;
        int x4 = (tid % XT_) << 2;
        size_t off = (size_t)(ty0 + y) * W + (tx0 + x4);
        m4[i] = *(const float4*)(mimg + off);
        p4[i] = *(const float4*)(pimg + off);
    }

    // ---- Phase 2: col prefix. 4 threads per column, SEG_ independent reads,
    //      register chain, in-wave shfl segment combine, write back. ----
    if (tid < 4 * HDIM_) {
        const int col = tid >> 2, seg = tid & 3;
        const int base = (seg * SEG_) * SCOLS_ + col;
        float v[SEG_];
        #pragma unroll
        for (int i = 0; i < SEG_; ++i) v[i] = sat[base + i * SCOLS_];
        #pragma unroll
        for (int i = 1; i < SEG_; ++i) v[i] += v[i - 1];
        float tot = v[SEG_ - 1];
        float inc = tot;
        float t1 = __shfl_up(inc, 1); if (seg >= 1) inc += t1;
        float t2 = __shfl_up(inc, 2); if (seg >= 2) inc += t2;
        const float off = inc - tot;
        #pragma unroll
        for (int i = 0; i < SEG_; ++i) sat[base + i * SCOLS_] = v[i] + off;
    }
    __syncthreads();

    // ---- Phase 3: per-pixel fused compute from the SAT. setprio(1): blocks on
    //      one CU sit at different phases; favor compute-phase waves. ----
    float s_w = 0.0f, s_wb = 0.0f, s_in = 0.0f, s_un = 0.0f, s_mae = 0.0f;

    const int pp[3]    = {1, 7, 15};
    const float inv[3] = {1.0f / 9.0f, 1.0f / 225.0f, 1.0f / 961.0f};

    __builtin_amdgcn_s_setprio(1);
    #pragma unroll
    for (int i = 0; i < GROUPS_; ++i) {
        const int rc = (tid / XT_) + RPG_ * i + 16;
        const int x4 = (tid % XT_) << 2;

        #pragma unroll
        for (int q = 0; q < 4; ++q) {
            float m  = (&m4[i].x)[q];
            float pr = (&p4[i].x)[q];
            int cc = x4 + q + 16;

            float w = 0.0f;
            #pragma unroll
            for (int j = 0; j < 3; ++j) {
                int r2 = (rc + pp[j]) * SCOLS_, r1 = (rc - pp[j] - 1) * SCOLS_;
                int c2 = cc + pp[j],            c1 = cc - pp[j] - 1;
                float s = sat[r2 + c2] - sat[r1 + c2]
                        - sat[r2 + c1] + sat[r1 + c1];
                w += fabsf(s * inv[j] - m);
            }
            float weit = 1.0f + 5.0f * w;
            float t    = __expf(-fabsf(pr));                 // shared by bce & sigmoid
            float bce  = fmaxf(pr, 0.0f) - pr * m + __logf(1.0f + t);
            float u    = __builtin_amdgcn_rcpf(1.0f + t);    // 1/(1+e^-|pr|)
            float sig  = (pr >= 0.0f) ? u : 1.0f - u;

            s_w   += weit;
            s_wb  += weit * bce;
            s_in  += sig * m * weit;
            s_un  += (sig + m) * weit;
            s_mae += fabsf(sig - m);
        }
    }
    __builtin_amdgcn_s_setprio(0);

    // ---- Phase 4: in-wave DPP reduction (VALU pipe), cross-wave via red[],
    //      then 5 plain stores to unique addresses ----
    s_w   = wave_sum_dpp(s_w);
    s_wb  = wave_sum_dpp(s_wb);
    s_in  = wave_sum_dpp(s_in);
    s_un  = wave_sum_dpp(s_un);
    s_mae = wave_sum_dpp(s_mae);

    int wave = tid >> 6, lane = tid & 63;
    if (lane == 63) {
        red[wave][0] = s_w;  red[wave][1] = s_wb; red[wave][2] = s_in;
        red[wave][3] = s_un; red[wave][4] = s_mae;
    }
    __syncthreads();
    if (tid < 5) {
        float r = 0.0f;
        #pragma unroll
        for (int wv = 0; wv < WAVES_; ++wv) r += red[wv][tid];
        const int tile = blockIdx.y * TX_ + blockIdx.x;
        const int ntiles = TX_ * (H / TILE_);
        part[((size_t)tid * BATCH + b) * ntiles + tile] = r;
    }
}

// Finalize: one block, 1024 threads. Wave w reduces batch w (ntiles tiles,
// coalesced comp-major loads), shuffle-reduce, thread 0 does the scalar epilogue.
__global__ __launch_bounds__(1024)
void adaptive_loss_finalize(const float* __restrict__ part,
                            float* __restrict__ out, int ntiles) {
    __shared__ float sums[BATCH][5];
    const int wv   = threadIdx.x >> 6;   // 0..15 == batch
    const int lane = threadIdx.x & 63;

    float v[5];
    #pragma unroll
    for (int c = 0; c < 5; ++c) {
        float s = 0.0f;
        for (int r = 0; r < ntiles / 64; ++r)
            s += part[((size_t)c * BATCH + wv) * ntiles + r * 64 + lane];
        v[c] = s;
    }
    #pragma unroll
    for (int off = 32; off > 0; off >>= 1) {
        #pragma unroll
        for (int c = 0; c < 5; ++c) v[c] += __shfl_down(v[c], off);
    }
    if (lane == 0) {
        #pragma unroll
        for (int c = 0; c < 5; ++c) sums[wv][c] = v[c];
    }
    __syncthreads();

    if (threadIdx.x == 0) {
        float smae = 0.0f;
        for (int b = 0; b < BATCH; ++b) smae += sums[b][4];
        float mae = smae / (float)((size_t)BATCH * H * W);
        float tot = 0.0f;
        for (int b = 0; b < BATCH; ++b) {
            float Sw  = sums[b][0];
            float Swb = sums[b][1];
            float Si  = sums[b][2];
            float Su  = sums[b][3];
            float wbce = Swb / Sw;
            float wiou = 1.0f - (Si + 1.0f) / (Su - Si + 1.0f);
            float wmae = mae * Sw / (Sw - (float)(H * W));
            tot += 0.7f * (wbce + wiou + wmae);
        }
        out[0] = tot / (float)BATCH;
    }
}

extern "C" void kernel_launch(void* const* d_in, const int* in_sizes, int n_in,
                              void* d_out, int out_size, void* d_ws, size_t ws_size,
                              hipStream_t stream) {
    const float* pred = (const float*)d_in[0];
    const float* mask = (const float*)d_in[1];
    float* part = (float*)d_ws;

    const size_t need32 = (size_t)5 * BATCH * (32 * 32) * sizeof(float);  // 320 KB
    if (ws_size == 0 || ws_size >= need32) {
        // TILE=32 path: 1024 tiles/batch, 16384 blocks of 256 threads.
        dim3 grid(W / 32, H / 32, BATCH);
        adaptive_loss_main<32, 256><<<grid, 256, 0, stream>>>(pred, mask, part);
        adaptive_loss_finalize<<<1, 1024, 0, stream>>>(part, (float*)d_out, 32 * 32);
    } else {
        // Fallback: proven TILE=64 path (80 KB workspace).
        dim3 grid(W / 64, H / 64, BATCH);
        adaptive_loss_main<64, 512><<<grid, 512, 0, stream>>>(pred, mask, part);
        adaptive_loss_finalize<<<1, 1024, 0, stream>>>(part, (float*)d_out, 16 * 16);
    }
}

// Round 8
// 176.546 us; speedup vs baseline: 1.1849x; 1.1849x over previous
//
#include <hip/hip_runtime.h>
#include <math.h>

// Problem constants (16 x 1 x 1024 x 1024 fp32 pred/mask -> scalar fp32 loss)
#define BATCH 16
#define H 1024
#define W 1024
#define TILE 64
#define TILES_X (W / TILE)            // 16
#define TILES_Y (H / TILE)            // 16
#define NTILES  (TILES_X * TILES_Y)   // 256 blocks per batch image
#define HDIM 96
#define SCOLS 97   // stride 97 % 32 == 1 -> scans and lookups land 2-way/bank max (free)
#define SEG  24    // scan segment length: 4 threads per 96-line

// d_ws: part[(c*BATCH + b)*NTILES + tile], c in [0,5) -- 80 KB. NO atomics
// (R4: contended atomicAdds serialized the GPU at ~115 atomics/us).
//
// R7 lessons: TILE=32 regressed (1.9x scan work, occupancy flat at ~60% -> the
// "residency" theory was wrong). Slack is intra-block convoy structure. R8 moves
// all SAT-independent work (exp/log/rcp/bce/sig/mae -- ~60% of old phase-3 VALU)
// into the phase-2 window, where waves 6-7 (idle through scans: 384/512 threads)
// and scan-wave load-latency bubbles absorb it. Phase 3 becomes corner-reads +
// weit + 4 fmas/px. Total work unchanged; it just fills the bubbles.

// DPP wave64 sum: lane 63 holds the full sum afterwards (VALU pipe, no LDS).
__device__ __forceinline__ float wave_sum_dpp(float x) {
    int t;
    t = __builtin_amdgcn_update_dpp(0, __float_as_int(x), 0x111, 0xf, 0xf, true); // row_shr:1
    x += __int_as_float(t);
    t = __builtin_amdgcn_update_dpp(0, __float_as_int(x), 0x112, 0xf, 0xf, true); // row_shr:2
    x += __int_as_float(t);
    t = __builtin_amdgcn_update_dpp(0, __float_as_int(x), 0x114, 0xf, 0xf, true); // row_shr:4
    x += __int_as_float(t);
    t = __builtin_amdgcn_update_dpp(0, __float_as_int(x), 0x118, 0xf, 0xf, true); // row_shr:8
    x += __int_as_float(t);
    t = __builtin_amdgcn_update_dpp(0, __float_as_int(x), 0x142, 0xf, 0xf, true); // row_bcast:15
    x += __int_as_float(t);
    t = __builtin_amdgcn_update_dpp(0, __float_as_int(x), 0x143, 0xf, 0xf, true); // row_bcast:31
    x += __int_as_float(t);
    return x;  // valid in lane 63
}

__global__ __launch_bounds__(512, 6)
void adaptive_loss_main(const float* __restrict__ pred,
                        const float* __restrict__ mask,
                        float* __restrict__ part) {
    __shared__ float sat[HDIM * SCOLS];
    __shared__ float red[8][5];

    const int tid = threadIdx.x;
    const int b   = blockIdx.z;
    const int ty0 = blockIdx.y * TILE;
    const int tx0 = blockIdx.x * TILE;
    const float* mimg = mask + (size_t)b * H * W;
    const float* pimg = pred + (size_t)b * H * W;

    // ---- Phase 0: issue ALL global loads up front. Scan loads first (needed
    //      first; vmcnt waits are ordered so waiting on them doesn't wait on
    //      the later m4/p4 loads). HBM latency hides under the prefix chain. ----
    float v[SEG];
    const int srow = tid >> 2, sseg = tid & 3;
    if (tid < 4 * HDIM) {
        const int gy  = ty0 - 16 + srow;
        const int gx0 = tx0 - 16 + sseg * SEG;
        const bool rowok = (gy >= 0) && (gy < H);
        const float* rp = mimg + (size_t)gy * W;
        #pragma unroll
        for (int j = 0; j < 6; ++j) {
            int gx = gx0 + 4 * j;                  // 16B-aligned; chunk fully in or out
            float4 t;
            if (rowok && gx >= 0 && gx < W) t = *(const float4*)(rp + gx);
            else                            t = make_float4(0.f, 0.f, 0.f, 0.f);
            v[4 * j + 0] = t.x; v[4 * j + 1] = t.y;
            v[4 * j + 2] = t.z; v[4 * j + 3] = t.w;
        }
    }
    float4 m4[2], p4[2];
    #pragma unroll
    for (int i = 0; i < 2; ++i) {
        int y  = (tid >> 4) + 32 * i;
        int x4 = (tid & 15) << 2;
        size_t off = (size_t)(ty0 + y) * W + (tx0 + x4);
        m4[i] = *(const float4*)(mimg + off);
        p4[i] = *(const float4*)(pimg + off);
    }

    // ---- Phase 1: row prefix in registers, shfl-combine 4 segment totals,
    //      write row-scanned values to LDS once (tid<384). ----
    if (tid < 4 * HDIM) {
        #pragma unroll
        for (int i = 1; i < SEG; ++i) v[i] += v[i - 1];
        float tot = v[SEG - 1];
        float inc = tot;
        float t1 = __shfl_up(inc, 1); if (sseg >= 1) inc += t1;
        float t2 = __shfl_up(inc, 2); if (sseg >= 2) inc += t2;
        const float off = inc - tot;
        const int base = srow * SCOLS + sseg * SEG;
        #pragma unroll
        for (int i = 0; i < SEG; ++i) sat[base + i] = v[i] + off;
    }
    __syncthreads();

    // ---- Precompute (ALL 512 threads; SAT-independent): transcendentals,
    //      bce, sigmoid, and the full mae accumulation. Runs in the phase-2
    //      window: waves 6-7 have nothing else, waves 0-5 interleave it with
    //      their scan latency. Results carried in regs into phase 3. ----
    float s_mae = 0.0f;
    float bq[8], iq[8], uq[8], mq[8];     // bce, sig*m, sig+m, m per pixel
    #pragma unroll
    for (int i = 0; i < 2; ++i) {
        #pragma unroll
        for (int q = 0; q < 4; ++q) {
            float m  = (&m4[i].x)[q];
            float pr = (&p4[i].x)[q];
            float t    = __expf(-fabsf(pr));
            float bce  = fmaxf(pr, 0.0f) - pr * m + __logf(1.0f + t);
            float u    = __builtin_amdgcn_rcpf(1.0f + t);
            float sig  = (pr >= 0.0f) ? u : 1.0f - u;
            bq[4 * i + q] = bce;
            iq[4 * i + q] = sig * m;
            uq[4 * i + q] = sig + m;
            mq[4 * i + q] = m;
            s_mae += fabsf(sig - m);
        }
    }

    // ---- Phase 2: col prefix (tid<384). 4 threads per column, register chain,
    //      in-wave shfl segment combine, write back. ----
    if (tid < 4 * HDIM) {
        const int col = tid >> 2, seg = tid & 3;
        const int base = (seg * SEG) * SCOLS + col;
        float w[SEG];
        #pragma unroll
        for (int i = 0; i < SEG; ++i) w[i] = sat[base + i * SCOLS];
        #pragma unroll
        for (int i = 1; i < SEG; ++i) w[i] += w[i - 1];
        float tot = w[SEG - 1];
        float inc = tot;
        float t1 = __shfl_up(inc, 1); if (seg >= 1) inc += t1;
        float t2 = __shfl_up(inc, 2); if (seg >= 2) inc += t2;
        const float off = inc - tot;
        #pragma unroll
        for (int i = 0; i < SEG; ++i) sat[base + i * SCOLS] = w[i] + off;
    }
    __syncthreads();

    // ---- Phase 3 (lean): corner reads + weit + 4 fmas per pixel. ----
    float s_w = 0.0f, s_wb = 0.0f, s_in = 0.0f, s_un = 0.0f;

    const int pp[3]    = {1, 7, 15};
    const float inv[3] = {1.0f / 9.0f, 1.0f / 225.0f, 1.0f / 961.0f};

    __builtin_amdgcn_s_setprio(1);
    #pragma unroll
    for (int i = 0; i < 2; ++i) {
        const int rc = (tid >> 4) + 32 * i + 16;
        const int x4 = (tid & 15) << 2;

        #pragma unroll
        for (int q = 0; q < 4; ++q) {
            const int cc = x4 + q + 16;
            const float m = mq[4 * i + q];

            float w = 0.0f;
            #pragma unroll
            for (int j = 0; j < 3; ++j) {
                int r2 = (rc + pp[j]) * SCOLS, r1 = (rc - pp[j] - 1) * SCOLS;
                int c2 = cc + pp[j],           c1 = cc - pp[j] - 1;
                float s = sat[r2 + c2] - sat[r1 + c2]
                        - sat[r2 + c1] + sat[r1 + c1];
                w += fabsf(s * inv[j] - m);
            }
            float weit = 1.0f + 5.0f * w;
            s_w  += weit;
            s_wb += weit * bq[4 * i + q];
            s_in += weit * iq[4 * i + q];
            s_un += weit * uq[4 * i + q];
        }
    }
    __builtin_amdgcn_s_setprio(0);

    // ---- Phase 4: DPP wave reduction (VALU pipe), cross-wave via red[],
    //      5 plain stores to unique addresses. ----
    s_w   = wave_sum_dpp(s_w);
    s_wb  = wave_sum_dpp(s_wb);
    s_in  = wave_sum_dpp(s_in);
    s_un  = wave_sum_dpp(s_un);
    s_mae = wave_sum_dpp(s_mae);

    int wave = tid >> 6, lane = tid & 63;
    if (lane == 63) {
        red[wave][0] = s_w;  red[wave][1] = s_wb; red[wave][2] = s_in;
        red[wave][3] = s_un; red[wave][4] = s_mae;
    }
    __syncthreads();
    if (tid < 5) {
        float r = 0.0f;
        #pragma unroll
        for (int wv = 0; wv < 8; ++wv) r += red[wv][tid];
        const int tile = blockIdx.y * TILES_X + blockIdx.x;
        part[((size_t)tid * BATCH + b) * NTILES + tile] = r;
    }
}

// Finalize: one block, 1024 threads. Wave w reduces batch w (256 tiles, 4 per
// lane, coalesced comp-major loads), shuffle-reduce, thread 0 scalar epilogue.
__global__ __launch_bounds__(1024)
void adaptive_loss_finalize(const float* __restrict__ part,
                            float* __restrict__ out) {
    __shared__ float sums[BATCH][5];
    const int wv   = threadIdx.x >> 6;   // 0..15 == batch
    const int lane = threadIdx.x & 63;

    float v[5];
    #pragma unroll
    for (int c = 0; c < 5; ++c) {
        float s = 0.0f;
        #pragma unroll
        for (int r = 0; r < NTILES / 64; ++r)
            s += part[((size_t)c * BATCH + wv) * NTILES + r * 64 + lane];
        v[c] = s;
    }
    #pragma unroll
    for (int off = 32; off > 0; off >>= 1) {
        #pragma unroll
        for (int c = 0; c < 5; ++c) v[c] += __shfl_down(v[c], off);
    }
    if (lane == 0) {
        #pragma unroll
        for (int c = 0; c < 5; ++c) sums[wv][c] = v[c];
    }
    __syncthreads();

    if (threadIdx.x == 0) {
        float smae = 0.0f;
        for (int b = 0; b < BATCH; ++b) smae += sums[b][4];
        float mae = smae / (float)((size_t)BATCH * H * W);
        float tot = 0.0f;
        for (int b = 0; b < BATCH; ++b) {
            float Sw  = sums[b][0];
            float Swb = sums[b][1];
            float Si  = sums[b][2];
            float Su  = sums[b][3];
            float wbce = Swb / Sw;
            float wiou = 1.0f - (Si + 1.0f) / (Su - Si + 1.0f);
            float wmae = mae * Sw / (Sw - (float)(H * W));
            tot += 0.7f * (wbce + wiou + wmae);
        }
        out[0] = tot / (float)BATCH;
    }
}

extern "C" void kernel_launch(void* const* d_in, const int* in_sizes, int n_in,
                              void* d_out, int out_size, void* d_ws, size_t ws_size,
                              hipStream_t stream) {
    const float* pred = (const float*)d_in[0];
    const float* mask = (const float*)d_in[1];
    float* part = (float*)d_ws;   // 5 * BATCH * NTILES floats = 80 KB

    dim3 grid(TILES_X, TILES_Y, BATCH);
    adaptive_loss_main<<<grid, 512, 0, stream>>>(pred, mask, part);
    adaptive_loss_finalize<<<1, 1024, 0, stream>>>(part, (float*)d_out);
}

// Round 9
// 164.903 us; speedup vs baseline: 1.2686x; 1.0706x over previous
//
#include <hip/hip_runtime.h>
#include <math.h>

// Problem constants (16 x 1 x 1024 x 1024 fp32 pred/mask -> scalar fp32 loss)
#define BATCH 16
#define H 1024
#define W 1024
#define TILE 64
#define TILES_X (W / TILE)            // 16
#define TILES_Y (H / TILE)            // 16
#define NTILES  (TILES_X * TILES_Y)   // 256 blocks per batch image
#define HDIM 96
#define SCOLS 97   // stride 97 % 32 == 1 -> scans and lookups land 2-way/bank max (free)
#define SEG  24    // scan segment length: 4 threads per 96-line

// d_ws: part[(c*BATCH + b)*NTILES + tile], c in [0,5) -- 80 KB. NO atomics
// (R4: contended atomicAdds serialized the GPU at ~115 atomics/us).
//
// Structure = R6 (best: 62.9us). R8's work-migration into phase 2 regressed:
// it lengthened the scan waves' (critical-path) serial work. R9 instead cuts
// phase-3 VALU: 6 base addresses per pixel-row (per {p}x{top,bottom}), all
// corner reads at COMPILE-TIME offsets from them -> one vaddr per base,
// ds_read2_b32 immediate-offset merging, ~1/8 the address arithmetic.

// DPP wave64 sum: lane 63 holds the full sum afterwards (VALU pipe, no LDS).
__device__ __forceinline__ float wave_sum_dpp(float x) {
    int t;
    t = __builtin_amdgcn_update_dpp(0, __float_as_int(x), 0x111, 0xf, 0xf, true); // row_shr:1
    x += __int_as_float(t);
    t = __builtin_amdgcn_update_dpp(0, __float_as_int(x), 0x112, 0xf, 0xf, true); // row_shr:2
    x += __int_as_float(t);
    t = __builtin_amdgcn_update_dpp(0, __float_as_int(x), 0x114, 0xf, 0xf, true); // row_shr:4
    x += __int_as_float(t);
    t = __builtin_amdgcn_update_dpp(0, __float_as_int(x), 0x118, 0xf, 0xf, true); // row_shr:8
    x += __int_as_float(t);
    t = __builtin_amdgcn_update_dpp(0, __float_as_int(x), 0x142, 0xf, 0xf, true); // row_bcast:15
    x += __int_as_float(t);
    t = __builtin_amdgcn_update_dpp(0, __float_as_int(x), 0x143, 0xf, 0xf, true); // row_bcast:31
    x += __int_as_float(t);
    return x;  // valid in lane 63
}

__global__ __launch_bounds__(512, 6)
void adaptive_loss_main(const float* __restrict__ pred,
                        const float* __restrict__ mask,
                        float* __restrict__ part) {
    __shared__ float sat[HDIM * SCOLS];
    __shared__ float red[8][5];

    const int tid = threadIdx.x;
    const int b   = blockIdx.z;
    const int ty0 = blockIdx.y * TILE;
    const int tx0 = blockIdx.x * TILE;
    const float* mimg = mask + (size_t)b * H * W;
    const float* pimg = pred + (size_t)b * H * W;

    // ---- Fused phase 0+1: load row segment straight from global (6x float4),
    //      prefix in registers, shfl-combine the 4 segment totals, write the
    //      row-scanned values to LDS once (tid<384). ----
    if (tid < 4 * HDIM) {
        const int row = tid >> 2, seg = tid & 3;
        const int gy  = ty0 - 16 + row;
        const int gx0 = tx0 - 16 + seg * SEG;
        const bool rowok = (gy >= 0) && (gy < H);
        const float* rp = mimg + (size_t)gy * W;

        float v[SEG];
        #pragma unroll
        for (int j = 0; j < 6; ++j) {
            int gx = gx0 + 4 * j;                  // 16B-aligned; chunk fully in or out
            float4 t;
            if (rowok && gx >= 0 && gx < W) t = *(const float4*)(rp + gx);
            else                            t = make_float4(0.f, 0.f, 0.f, 0.f);
            v[4 * j + 0] = t.x; v[4 * j + 1] = t.y;
            v[4 * j + 2] = t.z; v[4 * j + 3] = t.w;
        }
        #pragma unroll
        for (int i = 1; i < SEG; ++i) v[i] += v[i - 1];
        float tot = v[SEG - 1];
        float inc = tot;
        float t1 = __shfl_up(inc, 1); if (seg >= 1) inc += t1;
        float t2 = __shfl_up(inc, 2); if (seg >= 2) inc += t2;
        const float off = inc - tot;
        const int base = row * SCOLS + seg * SEG;
        #pragma unroll
        for (int i = 0; i < SEG; ++i) sat[base + i] = v[i] + off;
    }
    __syncthreads();

    // ---- Prefetch phase-3 operands into the col-scan latency window. ----
    float4 m4[2], p4[2];
    #pragma unroll
    for (int i = 0; i < 2; ++i) {
        int y  = (tid >> 4) + 32 * i;
        int x4 = (tid & 15) << 2;
        size_t off = (size_t)(ty0 + y) * W + (tx0 + x4);
        m4[i] = *(const float4*)(mimg + off);
        p4[i] = *(const float4*)(pimg + off);
    }

    // ---- Phase 2: col prefix (tid<384). 4 threads per column, register chain,
    //      in-wave shfl segment combine, write back. ----
    if (tid < 4 * HDIM) {
        const int col = tid >> 2, seg = tid & 3;
        const int base = (seg * SEG) * SCOLS + col;
        float v[SEG];
        #pragma unroll
        for (int i = 0; i < SEG; ++i) v[i] = sat[base + i * SCOLS];
        #pragma unroll
        for (int i = 1; i < SEG; ++i) v[i] += v[i - 1];
        float tot = v[SEG - 1];
        float inc = tot;
        float t1 = __shfl_up(inc, 1); if (seg >= 1) inc += t1;
        float t2 = __shfl_up(inc, 2); if (seg >= 2) inc += t2;
        const float off = inc - tot;
        #pragma unroll
        for (int i = 0; i < SEG; ++i) sat[base + i * SCOLS] = v[i] + off;
    }
    __syncthreads();

    // ---- Phase 3: per-pixel fused compute. Addressing: per pixel-row i and
    //      scale j, TWO bases (top/bottom SAT row at the col base, biased -16
    //      so all 4-q corner offsets are non-negative compile-time constants).
    //      All 12 corner reads per px become ds_read2_b32 immediates. ----
    float s_w = 0.0f, s_wb = 0.0f, s_in = 0.0f, s_un = 0.0f, s_mae = 0.0f;

    __builtin_amdgcn_s_setprio(1);
    #pragma unroll
    for (int i = 0; i < 2; ++i) {
        const int rc  = (tid >> 4) + 32 * i + 16;   // halo row of pixel
        const int x0c = ((tid & 15) << 2) + 16;     // halo col of pixel q=0

        float w[4] = {0.f, 0.f, 0.f, 0.f};

        #pragma unroll
        for (int j = 0; j < 3; ++j) {
            constexpr int PP[3] = {1, 7, 15};
            constexpr float INV[3] = {1.0f / 9.0f, 1.0f / 225.0f, 1.0f / 961.0f};
            const int p = PP[j];
            // biased bases: offsets for q in [0,4): c2 -> 16+p+q, c1 -> 15-p+q
            const int bt = (rc + p) * SCOLS + x0c - 16;      // top row (r2)
            const int bb = (rc - p - 1) * SCOLS + x0c - 16;  // bottom row (r1)
            #pragma unroll
            for (int q = 0; q < 4; ++q) {
                float s = sat[bt + (16 + p + q)] - sat[bb + (16 + p + q)]
                        - sat[bt + (15 - p + q)] + sat[bb + (15 - p + q)];
                w[q] += fabsf(s * INV[j] - (&m4[i].x)[q]);
            }
        }

        #pragma unroll
        for (int q = 0; q < 4; ++q) {
            float m  = (&m4[i].x)[q];
            float pr = (&p4[i].x)[q];
            float weit = 1.0f + 5.0f * w[q];
            float t    = __expf(-fabsf(pr));                 // shared by bce & sigmoid
            float bce  = fmaxf(pr, 0.0f) - pr * m + __logf(1.0f + t);
            float u    = __builtin_amdgcn_rcpf(1.0f + t);    // 1/(1+e^-|pr|)
            float sig  = (pr >= 0.0f) ? u : 1.0f - u;

            s_w   += weit;
            s_wb  += weit * bce;
            s_in  += sig * m * weit;
            s_un  += (sig + m) * weit;
            s_mae += fabsf(sig - m);
        }
    }
    __builtin_amdgcn_s_setprio(0);

    // ---- Phase 4: DPP wave reduction (VALU pipe), cross-wave via red[],
    //      5 plain stores to unique addresses. ----
    s_w   = wave_sum_dpp(s_w);
    s_wb  = wave_sum_dpp(s_wb);
    s_in  = wave_sum_dpp(s_in);
    s_un  = wave_sum_dpp(s_un);
    s_mae = wave_sum_dpp(s_mae);

    int wave = tid >> 6, lane = tid & 63;
    if (lane == 63) {
        red[wave][0] = s_w;  red[wave][1] = s_wb; red[wave][2] = s_in;
        red[wave][3] = s_un; red[wave][4] = s_mae;
    }
    __syncthreads();
    if (tid < 5) {
        float r = 0.0f;
        #pragma unroll
        for (int wv = 0; wv < 8; ++wv) r += red[wv][tid];
        const int tile = blockIdx.y * TILES_X + blockIdx.x;
        part[((size_t)tid * BATCH + b) * NTILES + tile] = r;
    }
}

// Finalize: one block, 1024 threads. Wave w reduces batch w (256 tiles, 4 per
// lane, coalesced comp-major loads), shuffle-reduce, thread 0 scalar epilogue.
__global__ __launch_bounds__(1024)
void adaptive_loss_finalize(const float* __restrict__ part,
                            float* __restrict__ out) {
    __shared__ float sums[BATCH][5];
    const int wv   = threadIdx.x >> 6;   // 0..15 == batch
    const int lane = threadIdx.x & 63;

    float v[5];
    #pragma unroll
    for (int c = 0; c < 5; ++c) {
        float s = 0.0f;
        #pragma unroll
        for (int r = 0; r < NTILES / 64; ++r)
            s += part[((size_t)c * BATCH + wv) * NTILES + r * 64 + lane];
        v[c] = s;
    }
    #pragma unroll
    for (int off = 32; off > 0; off >>= 1) {
        #pragma unroll
        for (int c = 0; c < 5; ++c) v[c] += __shfl_down(v[c], off);
    }
    if (lane == 0) {
        #pragma unroll
        for (int c = 0; c < 5; ++c) sums[wv][c] = v[c];
    }
    __syncthreads();

    if (threadIdx.x == 0) {
        float smae = 0.0f;
        for (int b = 0; b < BATCH; ++b) smae += sums[b][4];
        float mae = smae / (float)((size_t)BATCH * H * W);
        float tot = 0.0f;
        for (int b = 0; b < BATCH; ++b) {
            float Sw  = sums[b][0];
            float Swb = sums[b][1];
            float Si  = sums[b][2];
            float Su  = sums[b][3];
            float wbce = Swb / Sw;
            float wiou = 1.0f - (Si + 1.0f) / (Su - Si + 1.0f);
            float wmae = mae * Sw / (Sw - (float)(H * W));
            tot += 0.7f * (wbce + wiou + wmae);
        }
        out[0] = tot / (float)BATCH;
    }
}

extern "C" void kernel_launch(void* const* d_in, const int* in_sizes, int n_in,
                              void* d_out, int out_size, void* d_ws, size_t ws_size,
                              hipStream_t stream) {
    const float* pred = (const float*)d_in[0];
    const float* mask = (const float*)d_in[1];
    float* part = (float*)d_ws;   // 5 * BATCH * NTILES floats = 80 KB

    dim3 grid(TILES_X, TILES_Y, BATCH);
    adaptive_loss_main<<<grid, 512, 0, stream>>>(pred, mask, part);
    adaptive_loss_finalize<<<1, 1024, 0, stream>>>(part, (float*)d_out);
}